// Round 3
// baseline (395.324 us; speedup 1.0000x reference)
//
#include <hip/hip_runtime.h>

// image (8,256,64,64) f32, boxes (1000,4) f32, box_ind (1000,) i32
// out (1000,256,14,14) f32
constexpr int CROP_H = 14, CROP_W = 14, PIX = CROP_H * CROP_W;   // 196
constexpr int IMG_C = 256, IMG_H = 64, IMG_W = 64, PLANE = IMG_H * IMG_W;
constexpr int N_BOX = 1000;
constexpr int CSPLIT = 2;                  // channel splits per box
constexpr int CPB = IMG_C / CSPLIT;        // 128 channels per block

// Stage one contiguous row-band (nbytes, multiple of 256B) of a channel plane
// into LDS via async global->LDS DMA. dest = ldsbase + j*1024 + lane*16,
// matching the contiguous source chunk exactly (no padding allowed).
__device__ __forceinline__ void stage_band(const char* gsrc, char* ldsbase,
                                           int nbytes, int nchunk,
                                           int wave, int lane) {
    for (int j = wave; j < nchunk; j += 4) {
        int off = (j << 10) + (lane << 4);
        if (off < nbytes) {
            __builtin_amdgcn_global_load_lds(
                (const __attribute__((address_space(1))) void*)(gsrc + off),
                (__attribute__((address_space(3))) void*)(ldsbase + (j << 10)),
                16, 0, 0);
        }
    }
}

__global__ __launch_bounds__(256) void CropAndResize_5669356832751_kernel(
    const float* __restrict__ image,
    const float* __restrict__ boxes,
    const int*   __restrict__ box_ind,
    float* __restrict__ out)
{
    __shared__ float tile[2][PLANE];       // 2 x 16 KB, stride 64 (no pad: DMA constraint)

    const int n    = blockIdx.x;
    const int c0   = blockIdx.y * CPB;
    const int t    = threadIdx.x;
    const int wave = t >> 6;
    const int lane = t & 63;

    const float y1 = boxes[4*n+0], x1 = boxes[4*n+1];
    const float y2 = boxes[4*n+2], x2 = boxes[4*n+3];
    const int   b  = box_ind[n];

    const float hs = (y2 - y1) * (63.0f / 13.0f);
    const float ws = (x2 - x1) * (63.0f / 13.0f);

    // Row band for the whole box: in_y is monotone in py, so endpoints bound it.
    const float ey0 = fminf(fmaxf(y1 * 63.0f, 0.0f), 63.0f);
    const float ey1 = fminf(fmaxf(y2 * 63.0f, 0.0f), 63.0f);
    const int r0   = min((int)ey0, 62);
    const int r1   = min((int)ey1, 62);
    const int rmin = min(r0, r1);
    const int rmax = max(r0, r1) + 1;                  // inclusive
    const int nbytes = (rmax - rmin + 1) * (IMG_W * 4); // <= 16384, multiple of 256
    const int nchunk = (nbytes + 1023) >> 10;

    // Per-pixel sampling setup (valid for t < PIX; others compute garbage, unused)
    const int py = t / CROP_W;
    const int px = t - py * CROP_W;
    const float in_y = y1 * 63.0f + (float)py * hs;
    const float in_x = x1 * 63.0f + (float)px * ws;
    const bool oob = (in_y < 0.0f) | (in_y > 63.0f) | (in_x < 0.0f) | (in_x > 63.0f);
    const float cy = fminf(fmaxf(in_y, 0.0f), 63.0f);
    const float cx = fminf(fmaxf(in_x, 0.0f), 63.0f);
    const int row0 = min((int)cy, 62);
    const int col0 = min((int)cx, 62);
    const float yl = cy - (float)row0;
    const float xl = cx - (float)col0;
    const float m  = oob ? 0.0f : 1.0f;
    const float w00 = (1.0f - xl) * (1.0f - yl) * m;
    const float w01 = xl * (1.0f - yl) * m;
    const float w10 = (1.0f - xl) * yl * m;
    const float w11 = xl * yl * m;
    const int base = (row0 - rmin) * IMG_W + col0;

    // Source band of channel c0 (bands for c0+c are +c*PLANE floats)
    const char* src0 = (const char*)(image
        + ((size_t)b * IMG_C + c0) * PLANE + (size_t)rmin * IMG_W);
    float* outp = out + ((size_t)n * IMG_C + c0) * PIX + t;

    // Prime the pipeline: stage channel 0
    stage_band(src0, (char*)&tile[0][0], nbytes, nchunk, wave, lane);
    __syncthreads();

    for (int c = 0; c < CPB; ++c) {
        const float* cur = tile[c & 1];
        // Prefetch channel c+1 into the other buffer (drained by the barrier
        // below, after the compute phase has had time to overlap).
        if (c + 1 < CPB) {
            stage_band(src0 + (size_t)(c + 1) * (PLANE * 4),
                       (char*)&tile[(c + 1) & 1][0], nbytes, nchunk, wave, lane);
        }
        if (t < PIX) {
            float v = cur[base]           * w00 + cur[base + 1]         * w01
                    + cur[base + IMG_W]   * w10 + cur[base + IMG_W + 1] * w11;
            outp[(size_t)c * PIX] = v;
        }
        __syncthreads();
    }
}

extern "C" void kernel_launch(void* const* d_in, const int* in_sizes, int n_in,
                              void* d_out, int out_size, void* d_ws, size_t ws_size,
                              hipStream_t stream) {
    const float* image   = (const float*)d_in[0];
    const float* boxes   = (const float*)d_in[1];
    const int*   box_ind = (const int*)d_in[2];
    float* out = (float*)d_out;

    dim3 grid(N_BOX, CSPLIT);
    CropAndResize_5669356832751_kernel<<<grid, 256, 0, stream>>>(
        image, boxes, box_ind, out);
}